// Round 19
// baseline (73.898 us; speedup 1.0000x reference)
//
#include <hip/hip_runtime.h>

#define SLEN 4096
#define DDIM 128
#define BATCH 4
#define KROWS 256              // k-rows resident in LDS per block
#define NKB (SLEN / KROWS)     // 16 k-blocks per batch
#define QROWS 256              // q-rows per block (8 waves x 32)
#define NQR (SLEN / QROWS)     // 16 q-ranges per batch
#define NW 8                   // waves per block (512 threads)
#define SCLOG2E 0.12751743f    // log2(e)/sqrt(128), folded into Q in k1

typedef __bf16 v8bf __attribute__((ext_vector_type(8)));
typedef float f32x4 __attribute__((ext_vector_type(4)));

__device__ __forceinline__ f32x4 mfma16(v8bf a, v8bf b, f32x4 c) {
  return __builtin_amdgcn_mfma_f32_16x16x32_bf16(a, b, c, 0, 0, 0);
}

__device__ __forceinline__ void gload_lds16(const void* g, void* l) {
  __builtin_amdgcn_global_load_lds(
      (const __attribute__((address_space(1))) unsigned int*)g,
      (__attribute__((address_space(3))) unsigned int*)l, 16, 0, 0);
}

// Decode blockIdx so the 16 k-blocks of one (batch, q-range) land on one XCD
// (XCD = bid%8 dispatch heuristic; wrong mapping costs only L3 hits).
__device__ __forceinline__ void decode_bid(int bid, int& b, int& qr, int& kblk) {
  int x = bid & 7;           // XCD
  int i = bid >> 3;          // 0..127
  int pr = x * 8 + (i >> 4); // (b,qr) pair 0..63, 8 pairs per XCD
  kblk = i & 15;
  b = pr >> 4;
  qr = pr & 15;
}

// Stage the 256-row K-slab (64 KB) into LDS with 8 waves, XOR-swizzled
// (verified R4-R18). Phys 16B slot pp of row r holds logical slot pp^(r&7);
// swizzle applied on the per-lane GLOBAL source, LDS dest linear (rule #21).
__device__ __forceinline__ void stage_kslab(const __bf16* __restrict__ Krow0,
                                            char* buf, int wave, int lane) {
#pragma unroll
  for (int it = 0; it < 8; ++it) {
    int s = it * 512 + wave * 64 + lane;   // 16B slot 0..4095
    int r = s >> 4;                        // k-row 0..255
    int pp = s & 15;
    int lsl = pp ^ (r & 7);
    const __bf16* src = Krow0 + (size_t)r * DDIM + lsl * 8;
    char* dst = buf + (size_t)(it * 512 + wave * 64) * 16;  // wave-uniform
    gload_lds16(src, dst);
  }
}

// Read one tile's 4 K fragments (issued ahead of the consuming MFMAs so the
// auto-inserted waitcnt is a partial lgkmcnt, not a drain).
__device__ __forceinline__ void read4(v8bf k[4], const char* const pa[4], int t) {
  int off = t << 12;   // t * 4096 bytes
#pragma unroll
  for (int h = 0; h < 4; ++h)
    k[h] = *reinterpret_cast<const v8bf*>(pa[h] + off);
}

// 8 MFMA (qs=2) on one tile's fragments.
__device__ __forceinline__ void mfma8(f32x4 A[2], const v8bf qf[2][4],
                                      const v8bf k[4]) {
  A[0] = (f32x4){0.f, 0.f, 0.f, 0.f};
  A[1] = (f32x4){0.f, 0.f, 0.f, 0.f};
#pragma unroll
  for (int h = 0; h < 4; ++h) {
    A[0] = mfma16(qf[0][h], k[h], A[0]);
    A[1] = mfma16(qf[1][h], k[h], A[1]);
  }
}

// Scores pre-scaled (Q carries log2e/sqrt(128)): exp path = v_exp + v_add.
__device__ __forceinline__ void consume_z(const f32x4 A[2], float zacc[2][4]) {
#pragma unroll
  for (int qs = 0; qs < 2; ++qs)
#pragma unroll
    for (int j = 0; j < 4; ++j)
      zacc[qs][j] += exp2f(A[qs][j]);
}

// ---------------------------------------------------------------------------
// k1: projections Q = (x@Wq + bq)*SCLOG2E, K = x@Wk + bk  -> bf16, via MFMA.
// k0 folded in: each block packs Wq|Wk into MFMA B-fragment layout directly
// in LDS (Wq/Wk are 128 KB total, L2-resident).
__global__ __launch_bounds__(256) void k1_proj(const float* __restrict__ x,
                                               const float* __restrict__ Wq,
                                               const float* __restrict__ Wk,
                                               const float* __restrict__ bq,
                                               const float* __restrict__ bk,
                                               __bf16* __restrict__ Qb,
                                               __bf16* __restrict__ Kb) {
  int wave = threadIdx.x >> 6, lane = threadIdx.x & 63;
  int lr = lane & 15, lg = lane >> 4;

  __shared__ __align__(16) char wlds[64 * 1024];

  // pack Wt into LDS (same mapping as the old k0 kernel)
#pragma unroll
  for (int it = 0; it < 16; ++it) {
    int idx = it * 256 + threadIdx.x;   // 0..4095
    int ct = idx >> 8;
    int hs = (idx >> 6) & 3;
    int l  = idx & 63;
    int col = ((ct & 7) << 4) + (l & 15);
    const float* W = (ct < 8) ? Wq : Wk;
    int hbase = hs * 32 + (l >> 4) * 8;
    v8bf t;
#pragma unroll
    for (int i = 0; i < 8; ++i)
      t[i] = (__bf16)W[(hbase + i) * DDIM + col];
    *reinterpret_cast<v8bf*>(wlds + (size_t)idx * 16) = t;
  }

  int r0 = blockIdx.x * 64 + wave * 16;      // flat row over B*S
  const float* xrow = x + (size_t)(r0 + lr) * DDIM;

  v8bf xf[4];
#pragma unroll
  for (int hs = 0; hs < 4; ++hs) {
    float4 a = *reinterpret_cast<const float4*>(xrow + hs * 32 + lg * 8);
    float4 c = *reinterpret_cast<const float4*>(xrow + hs * 32 + lg * 8 + 4);
    v8bf t;
    t[0] = (__bf16)a.x; t[1] = (__bf16)a.y; t[2] = (__bf16)a.z; t[3] = (__bf16)a.w;
    t[4] = (__bf16)c.x; t[5] = (__bf16)c.y; t[6] = (__bf16)c.z; t[7] = (__bf16)c.w;
    xf[hs] = t;
  }

  __syncthreads();

  for (int ct = 0; ct < 16; ++ct) {
    f32x4 acc = {0.f, 0.f, 0.f, 0.f};
#pragma unroll
    for (int hs = 0; hs < 4; ++hs) {
      v8bf wf = *reinterpret_cast<const v8bf*>(
          wlds + (size_t)((ct * 4 + hs) * 64 + lane) * 16);
      acc = mfma16(xf[hs], wf, acc);
    }
    int col = ((ct & 7) << 4) + lr;
    float bias = (ct < 8) ? bq[col] : bk[col];
    float sc   = (ct < 8) ? SCLOG2E : 1.0f;   // fold exp2-domain scale into Q
    __bf16* dst = (ct < 8) ? Qb : Kb;
#pragma unroll
    for (int j = 0; j < 4; ++j) {
      int row = r0 + lg * 4 + j;
      dst[(size_t)row * DDIM + col] = (__bf16)((acc[j] + bias) * sc);
    }
  }
}

// ---------------------------------------------------------------------------
// k2a: partial softmax denominators, K-resident. Block (b,qr,kblk): K-slab
// staged once; 8 waves each own 32 disjoint q-rows. 3-buffer kA/kB/kC
// prefetch: a tile's fragments are read ~2 tiles (300-400 cy of issue work)
// before consumption; 3 acc sets keep exp off each MFMA chain's tail.
__global__ __launch_bounds__(512, 4) void k2a_z(const __bf16* __restrict__ Qb,
                                                const __bf16* __restrict__ Kb,
                                                float* __restrict__ zpart) {
  int b, qr, kblk;
  decode_bid(blockIdx.x, b, qr, kblk);
  int p = b * NQR + qr;
  int wave = threadIdx.x >> 6, lane = threadIdx.x & 63;
  int lr = lane & 15, lg = lane >> 4;

  __shared__ __align__(16) char kbuf[KROWS * 256];  // 64 KB

  stage_kslab(Kb + ((size_t)b * SLEN + kblk * KROWS) * DDIM, kbuf, wave, lane);

  int qloc0 = wave * 32;
  const __bf16* Qp = Qb + ((size_t)b * SLEN + qr * QROWS + qloc0) * DDIM;

  v8bf qf[2][4];
#pragma unroll
  for (int qs = 0; qs < 2; ++qs)
#pragma unroll
    for (int hs = 0; hs < 4; ++hs)
      qf[qs][hs] = *reinterpret_cast<const v8bf*>(Qp + (size_t)(qs * 16 + lr) * DDIM + hs * 32 + lg * 8);

  // persistent per-lane LDS base addresses (swizzled); tile adds t<<12
  const char* pa[4];
#pragma unroll
  for (int hs = 0; hs < 4; ++hs)
    pa[hs] = kbuf + lr * 256 + (((hs * 4 + lg) ^ (lr & 7)) << 4);

  float zacc[2][4];
#pragma unroll
  for (int qs = 0; qs < 2; ++qs)
#pragma unroll
    for (int j = 0; j < 4; ++j) zacc[qs][j] = 0.f;

  __syncthreads();

  v8bf kA[4], kB[4], kC[4];
  f32x4 aA[2], aB[2], aC[2];
  read4(kA, pa, 0);
  read4(kB, pa, 1);
  read4(kC, pa, 2);
#pragma unroll 1
  for (int i = 0; i < 4; ++i) {   // tiles 3i, 3i+1, 3i+2; reads 2 tiles ahead
    mfma8(aA, qf, kA);            // t(3i)   — kA landed >=2 tiles ago
    read4(kA, pa, 3 * i + 3);
    mfma8(aB, qf, kB);            // t(3i+1)
    consume_z(aA, zacc);
    read4(kB, pa, 3 * i + 4);
    mfma8(aC, qf, kC);            // t(3i+2)
    consume_z(aB, zacc);
    read4(kC, pa, 3 * i + 5);
    consume_z(aC, zacc);
  }
  // epilogue: tiles 12..15 (kA=t12, kB=t13, kC=t14 already in flight)
  mfma8(aA, qf, kA);              // t12
  read4(kA, pa, 15);
  mfma8(aB, qf, kB);              // t13
  consume_z(aA, zacc);
  mfma8(aC, qf, kC);              // t14
  consume_z(aB, zacc);
  mfma8(aA, qf, kA);              // t15
  consume_z(aC, zacc);
  consume_z(aA, zacc);

  // row-sum over the 16 lr lanes (k columns)
#pragma unroll
  for (int qs = 0; qs < 2; ++qs)
#pragma unroll
    for (int j = 0; j < 4; ++j) {
      float z = zacc[qs][j];
      z += __shfl_xor(z, 1);
      z += __shfl_xor(z, 2);
      z += __shfl_xor(z, 4);
      z += __shfl_xor(z, 8);
      if (lr == 0)
        zpart[((size_t)p * NKB + kblk) * QROWS + qloc0 + qs * 16 + lg * 4 + j] = z;
    }
}

// ---------------------------------------------------------------------------
// k2c: column weights, K-resident, 2-buffer prefetch pipeline (iz registers
// preclude the 3-buffer variant within the 128-VGPR cap); per-tile result
// written to LDS warr (runtime LDS address is fine; registers stay static).
__global__ __launch_bounds__(512, 4) void k2c_w(const __bf16* __restrict__ Qb,
                                                const __bf16* __restrict__ Kb,
                                                const float* __restrict__ zpart,
                                                float* __restrict__ wpart) {
  int b, qr, kblk;
  decode_bid(blockIdx.x, b, qr, kblk);
  int p = b * NQR + qr;
  int wave = threadIdx.x >> 6, lane = threadIdx.x & 63;
  int lr = lane & 15, lg = lane >> 4;

  __shared__ __align__(16) char kbuf[KROWS * 256];  // 64 KB
  __shared__ float invZ[QROWS];                     // 1 KB
  __shared__ float warr[NW][KROWS];                 // 8 KB

  stage_kslab(Kb + ((size_t)b * SLEN + kblk * KROWS) * DDIM, kbuf, wave, lane);

  // full-Z gather for this q-range (sums the 16 k-blocks' partials)
  if (threadIdx.x < QROWS) {
    const float* zp = zpart + (size_t)p * NKB * QROWS + threadIdx.x;
    float z = 0.f;
#pragma unroll
    for (int kb = 0; kb < NKB; ++kb) z += zp[(size_t)kb * QROWS];
    invZ[threadIdx.x] = 1.0f / z;
  }
  __syncthreads();

  int qloc0 = wave * 32;
  const __bf16* Qp = Qb + ((size_t)b * SLEN + qr * QROWS + qloc0) * DDIM;

  v8bf qf[2][4];
#pragma unroll
  for (int qs = 0; qs < 2; ++qs)
#pragma unroll
    for (int hs = 0; hs < 4; ++hs)
      qf[qs][hs] = *reinterpret_cast<const v8bf*>(Qp + (size_t)(qs * 16 + lr) * DDIM + hs * 32 + lg * 8);

  float iz[2][4];
#pragma unroll
  for (int qs = 0; qs < 2; ++qs)
#pragma unroll
    for (int j = 0; j < 4; ++j)
      iz[qs][j] = invZ[qloc0 + qs * 16 + lg * 4 + j];

  const char* pa[4];
#pragma unroll
  for (int hs = 0; hs < 4; ++hs)
    pa[hs] = kbuf + lr * 256 + (((hs * 4 + lg) ^ (lr & 7)) << 4);

  float* wbase = &warr[wave][lr];

  auto cw = [&](const f32x4 A[2], int t) {
    float wk = 0.f;
#pragma unroll
    for (int qs = 0; qs < 2; ++qs)
#pragma unroll
      for (int j = 0; j < 4; ++j)
        wk += exp2f(A[qs][j]) * iz[qs][j];
    wk += __shfl_xor(wk, 16);
    wk += __shfl_xor(wk, 32);
    if (lg == 0) wbase[t * 16] = wk;
  };

  v8bf kA[4], kB[4];
  f32x4 aA[2], aB[2];
  read4(kA, pa, 0);
  read4(kB, pa, 1);
  mfma8(aA, qf, kA);          // t0
#pragma unroll 1
  for (int i = 0; i < 7; ++i) {
    read4(kA, pa, 2 * i + 2);
    mfma8(aB, qf, kB);        // t(2i+1)
    cw(aA, 2 * i);            // t(2i)
    read4(kB, pa, 2 * i + 3);
    mfma8(aA, qf, kA);        // t(2i+2)
    cw(aB, 2 * i + 1);        // t(2i+1)
  }
  mfma8(aB, qf, kB);          // t15
  cw(aA, 14);
  cw(aB, 15);

  __syncthreads();
  if (threadIdx.x < KROWS) {
    int k = threadIdx.x;
    float s = 0.f;
#pragma unroll
    for (int w = 0; w < NW; ++w) s += warr[w][k];
    wpart[(size_t)p * SLEN + kblk * KROWS + k] = s;
  }
}

// ---------------------------------------------------------------------------
// k4: fused column-sum (16 q-range slabs) + weighted x reduction.
// 16x4 blocks x 256 threads: block (b, kc) covers 256 k-rows.
__global__ __launch_bounds__(256) void k4_u(const float* __restrict__ x,
                                            const float* __restrict__ wpart,
                                            float* __restrict__ upart) {
  int b = blockIdx.y, kc = blockIdx.x;   // kc: 16 chunks of 256 k
  int t = threadIdx.x;
  __shared__ float ws[256];
  {
    const float* pw = wpart + (size_t)b * NQR * SLEN + kc * 256 + t;
    float s = 0.f;
#pragma unroll
    for (int j = 0; j < NQR; ++j) s += pw[(size_t)j * SLEN];
    ws[t] = s;
  }
  __syncthreads();
  int d = t & 127, kh = t >> 7;   // 2 k-halves of 128
  const float* xb = x + ((size_t)b * SLEN + kc * 256 + kh * 128) * DDIM;
  float acc = 0.f;
  for (int kk = 0; kk < 128; ++kk)
    acc += ws[kh * 128 + kk] * xb[(size_t)kk * DDIM + d];
  upart[((size_t)b * 32 + kc * 2 + kh) * DDIM + d] = acc;
}

// ---------------------------------------------------------------------------
// k5: out[b,d] = (1/S) * (u[b,:] @ Wv[:,d]) + bv[d]
__global__ __launch_bounds__(128) void k5_out(const float* __restrict__ upart,
                                              const float* __restrict__ Wv,
                                              const float* __restrict__ bv,
                                              float* __restrict__ out) {
  int b = blockIdx.x, d = threadIdx.x;
  __shared__ float u[DDIM];
  float s = 0.f;
  for (int c = 0; c < 32; ++c) s += upart[((size_t)b * 32 + c) * DDIM + d];
  u[d] = s;
  __syncthreads();
  float acc = 0.f;
  for (int dp = 0; dp < DDIM; ++dp) acc += u[dp] * Wv[(size_t)dp * DDIM + d];
  out[b * DDIM + d] = acc * (1.0f / SLEN) + bv[d];
}

// ---------------------------------------------------------------------------
extern "C" void kernel_launch(void* const* d_in, const int* in_sizes, int n_in,
                              void* d_out, int out_size, void* d_ws, size_t ws_size,
                              hipStream_t stream) {
  const float* x  = (const float*)d_in[0];
  const float* Wq = (const float*)d_in[1];
  const float* bq = (const float*)d_in[2];
  const float* Wk = (const float*)d_in[3];
  const float* bk = (const float*)d_in[4];
  const float* Wv = (const float*)d_in[5];
  const float* bv = (const float*)d_in[6];
  float* out = (float*)d_out;

  char* ws = (char*)d_ws;
  __bf16* Qb    = (__bf16*)(ws);                                  // 4 MB
  __bf16* Kb    = (__bf16*)(ws + (4u << 20));                     // 4 MB
  float*  zpart = (float*)(ws + (8u << 20));                      // 1 MB
  float*  wpart = (float*)(ws + (9u << 20));                      // 1 MB
  float*  upart = (float*)(ws + (10u << 20));                     // 64 KB

  k1_proj<<<256, 256, 0, stream>>>(x, Wq, Wk, bq, bk, Qb, Kb);
  k2a_z  <<<NKB * NQR * BATCH, 512, 0, stream>>>(Qb, Kb, zpart);
  k2c_w  <<<NKB * NQR * BATCH, 512, 0, stream>>>(Qb, Kb, zpart, wpart);
  k4_u   <<<dim3(16, BATCH), 256, 0, stream>>>(x, wpart, upart);
  k5_out <<<BATCH, 128, 0, stream>>>(upart, Wv, bv, out);
}

// Round 20
// 72.424 us; speedup vs baseline: 1.0203x; 1.0203x over previous
//
#include <hip/hip_runtime.h>

#define SLEN 4096
#define DDIM 128
#define BATCH 4
#define KROWS 256              // k-rows resident in LDS per block
#define NKB (SLEN / KROWS)     // 16 k-blocks per batch
#define QROWS 256              // q-rows per block (8 waves x 32)
#define NQR (SLEN / QROWS)     // 16 q-ranges per batch
#define NW 8                   // waves per block (512 threads)
#define SCLOG2E 0.12751743f    // log2(e)/sqrt(128), folded into Q in k1

typedef __bf16 v8bf __attribute__((ext_vector_type(8)));
typedef float f32x4 __attribute__((ext_vector_type(4)));

__device__ __forceinline__ f32x4 mfma16(v8bf a, v8bf b, f32x4 c) {
  return __builtin_amdgcn_mfma_f32_16x16x32_bf16(a, b, c, 0, 0, 0);
}

__device__ __forceinline__ void gload_lds16(const void* g, void* l) {
  __builtin_amdgcn_global_load_lds(
      (const __attribute__((address_space(1))) unsigned int*)g,
      (__attribute__((address_space(3))) unsigned int*)l, 16, 0, 0);
}

// Decode blockIdx so the 16 k-blocks of one (batch, q-range) land on one XCD
// (XCD = bid%8 dispatch heuristic; wrong mapping costs only L3 hits).
__device__ __forceinline__ void decode_bid(int bid, int& b, int& qr, int& kblk) {
  int x = bid & 7;           // XCD
  int i = bid >> 3;          // 0..127
  int pr = x * 8 + (i >> 4); // (b,qr) pair 0..63, 8 pairs per XCD
  kblk = i & 15;
  b = pr >> 4;
  qr = pr & 15;
}

// Stage the 256-row K-slab (64 KB) into LDS with 8 waves, XOR-swizzled
// (verified R4-R18). Phys 16B slot pp of row r holds logical slot pp^(r&7);
// swizzle applied on the per-lane GLOBAL source, LDS dest linear (rule #21).
__device__ __forceinline__ void stage_kslab(const __bf16* __restrict__ Krow0,
                                            char* buf, int wave, int lane) {
#pragma unroll
  for (int it = 0; it < 8; ++it) {
    int s = it * 512 + wave * 64 + lane;   // 16B slot 0..4095
    int r = s >> 4;                        // k-row 0..255
    int pp = s & 15;
    int lsl = pp ^ (r & 7);
    const __bf16* src = Krow0 + (size_t)r * DDIM + lsl * 8;
    char* dst = buf + (size_t)(it * 512 + wave * 64) * 16;  // wave-uniform
    gload_lds16(src, dst);
  }
}

// Read one tile's 4 K fragments (issued ahead of the consuming MFMAs so the
// auto-inserted waitcnt is lgkmcnt(4), not a drain).
__device__ __forceinline__ void read4(v8bf k[4], const char* const pa[4], int t) {
  int off = t << 12;   // t * 4096 bytes
#pragma unroll
  for (int h = 0; h < 4; ++h)
    k[h] = *reinterpret_cast<const v8bf*>(pa[h] + off);
}

// 8 MFMA (qs=2) on one tile's fragments.
__device__ __forceinline__ void mfma8(f32x4 A[2], const v8bf qf[2][4],
                                      const v8bf k[4]) {
  A[0] = (f32x4){0.f, 0.f, 0.f, 0.f};
  A[1] = (f32x4){0.f, 0.f, 0.f, 0.f};
#pragma unroll
  for (int h = 0; h < 4; ++h) {
    A[0] = mfma16(qf[0][h], k[h], A[0]);
    A[1] = mfma16(qf[1][h], k[h], A[1]);
  }
}

// Scores pre-scaled (Q carries log2e/sqrt(128)): exp path = v_exp + v_add.
__device__ __forceinline__ void consume_z(const f32x4 A[2], float zacc[2][4]) {
#pragma unroll
  for (int qs = 0; qs < 2; ++qs)
#pragma unroll
    for (int j = 0; j < 4; ++j)
      zacc[qs][j] += exp2f(A[qs][j]);
}

// ---------------------------------------------------------------------------
// k1: projections Q = (x@Wq + bq)*SCLOG2E, K = x@Wk + bk  -> bf16, via MFMA.
// k0 folded in: each block packs Wq|Wk into MFMA B-fragment layout directly
// in LDS (Wq/Wk are 128 KB total, L2-resident).
__global__ __launch_bounds__(256) void k1_proj(const float* __restrict__ x,
                                               const float* __restrict__ Wq,
                                               const float* __restrict__ Wk,
                                               const float* __restrict__ bq,
                                               const float* __restrict__ bk,
                                               __bf16* __restrict__ Qb,
                                               __bf16* __restrict__ Kb) {
  int wave = threadIdx.x >> 6, lane = threadIdx.x & 63;
  int lr = lane & 15, lg = lane >> 4;

  __shared__ __align__(16) char wlds[64 * 1024];

  // pack Wt into LDS (same mapping as the old k0 kernel)
#pragma unroll
  for (int it = 0; it < 16; ++it) {
    int idx = it * 256 + threadIdx.x;   // 0..4095
    int ct = idx >> 8;
    int hs = (idx >> 6) & 3;
    int l  = idx & 63;
    int col = ((ct & 7) << 4) + (l & 15);
    const float* W = (ct < 8) ? Wq : Wk;
    int hbase = hs * 32 + (l >> 4) * 8;
    v8bf t;
#pragma unroll
    for (int i = 0; i < 8; ++i)
      t[i] = (__bf16)W[(hbase + i) * DDIM + col];
    *reinterpret_cast<v8bf*>(wlds + (size_t)idx * 16) = t;
  }

  int r0 = blockIdx.x * 64 + wave * 16;      // flat row over B*S
  const float* xrow = x + (size_t)(r0 + lr) * DDIM;

  v8bf xf[4];
#pragma unroll
  for (int hs = 0; hs < 4; ++hs) {
    float4 a = *reinterpret_cast<const float4*>(xrow + hs * 32 + lg * 8);
    float4 c = *reinterpret_cast<const float4*>(xrow + hs * 32 + lg * 8 + 4);
    v8bf t;
    t[0] = (__bf16)a.x; t[1] = (__bf16)a.y; t[2] = (__bf16)a.z; t[3] = (__bf16)a.w;
    t[4] = (__bf16)c.x; t[5] = (__bf16)c.y; t[6] = (__bf16)c.z; t[7] = (__bf16)c.w;
    xf[hs] = t;
  }

  __syncthreads();

  for (int ct = 0; ct < 16; ++ct) {
    f32x4 acc = {0.f, 0.f, 0.f, 0.f};
#pragma unroll
    for (int hs = 0; hs < 4; ++hs) {
      v8bf wf = *reinterpret_cast<const v8bf*>(
          wlds + (size_t)((ct * 4 + hs) * 64 + lane) * 16);
      acc = mfma16(xf[hs], wf, acc);
    }
    int col = ((ct & 7) << 4) + lr;
    float bias = (ct < 8) ? bq[col] : bk[col];
    float sc   = (ct < 8) ? SCLOG2E : 1.0f;   // fold exp2-domain scale into Q
    __bf16* dst = (ct < 8) ? Qb : Kb;
#pragma unroll
    for (int j = 0; j < 4; ++j) {
      int row = r0 + lg * 4 + j;
      dst[(size_t)row * DDIM + col] = (__bf16)((acc[j] + bias) * sc);
    }
  }
}

// ---------------------------------------------------------------------------
// k2a: partial softmax denominators, K-resident. Block (b,qr,kblk): K-slab
// staged once; 8 waves each own 32 disjoint q-rows. kA/kB register prefetch:
// tile i+1's ds_reads issue before tile i's MFMAs (waitcnt -> lgkmcnt(4)),
// a0/a1 acc pipeline overlaps exp of tile i-1 with MFMAs of tile i.
__global__ __launch_bounds__(512, 4) void k2a_z(const __bf16* __restrict__ Qb,
                                                const __bf16* __restrict__ Kb,
                                                float* __restrict__ zpart) {
  int b, qr, kblk;
  decode_bid(blockIdx.x, b, qr, kblk);
  int p = b * NQR + qr;
  int wave = threadIdx.x >> 6, lane = threadIdx.x & 63;
  int lr = lane & 15, lg = lane >> 4;

  __shared__ __align__(16) char kbuf[KROWS * 256];  // 64 KB

  stage_kslab(Kb + ((size_t)b * SLEN + kblk * KROWS) * DDIM, kbuf, wave, lane);

  int qloc0 = wave * 32;
  const __bf16* Qp = Qb + ((size_t)b * SLEN + qr * QROWS + qloc0) * DDIM;

  v8bf qf[2][4];
#pragma unroll
  for (int qs = 0; qs < 2; ++qs)
#pragma unroll
    for (int hs = 0; hs < 4; ++hs)
      qf[qs][hs] = *reinterpret_cast<const v8bf*>(Qp + (size_t)(qs * 16 + lr) * DDIM + hs * 32 + lg * 8);

  // persistent per-lane LDS base addresses (swizzled); tile adds t<<12
  const char* pa[4];
#pragma unroll
  for (int hs = 0; hs < 4; ++hs)
    pa[hs] = kbuf + lr * 256 + (((hs * 4 + lg) ^ (lr & 7)) << 4);

  float zacc[2][4];
#pragma unroll
  for (int qs = 0; qs < 2; ++qs)
#pragma unroll
    for (int j = 0; j < 4; ++j) zacc[qs][j] = 0.f;

  __syncthreads();

  v8bf kA[4], kB[4];
  f32x4 aA[2], aB[2];
  read4(kA, pa, 0);
  read4(kB, pa, 1);
  mfma8(aA, qf, kA);          // t0 (kB in flight -> lgkmcnt(4))
#pragma unroll 1
  for (int i = 0; i < 7; ++i) {
    read4(kA, pa, 2 * i + 2);
    mfma8(aB, qf, kB);        // t(2i+1)
    consume_z(aA, zacc);      // t(2i)
    read4(kB, pa, 2 * i + 3);
    mfma8(aA, qf, kA);        // t(2i+2)
    consume_z(aB, zacc);      // t(2i+1)
  }
  mfma8(aB, qf, kB);          // t15
  consume_z(aA, zacc);        // t14
  consume_z(aB, zacc);        // t15

  // row-sum over the 16 lr lanes (k columns)
#pragma unroll
  for (int qs = 0; qs < 2; ++qs)
#pragma unroll
    for (int j = 0; j < 4; ++j) {
      float z = zacc[qs][j];
      z += __shfl_xor(z, 1);
      z += __shfl_xor(z, 2);
      z += __shfl_xor(z, 4);
      z += __shfl_xor(z, 8);
      if (lr == 0)
        zpart[((size_t)p * NKB + kblk) * QROWS + qloc0 + qs * 16 + lg * 4 + j] = z;
    }
}

// ---------------------------------------------------------------------------
// k2c: column weights, K-resident, same prefetch pipeline; per-tile result
// written to LDS warr (runtime LDS address is fine; registers stay static).
__global__ __launch_bounds__(512, 4) void k2c_w(const __bf16* __restrict__ Qb,
                                                const __bf16* __restrict__ Kb,
                                                const float* __restrict__ zpart,
                                                float* __restrict__ wpart) {
  int b, qr, kblk;
  decode_bid(blockIdx.x, b, qr, kblk);
  int p = b * NQR + qr;
  int wave = threadIdx.x >> 6, lane = threadIdx.x & 63;
  int lr = lane & 15, lg = lane >> 4;

  __shared__ __align__(16) char kbuf[KROWS * 256];  // 64 KB
  __shared__ float invZ[QROWS];                     // 1 KB
  __shared__ float warr[NW][KROWS];                 // 8 KB

  stage_kslab(Kb + ((size_t)b * SLEN + kblk * KROWS) * DDIM, kbuf, wave, lane);

  // full-Z gather for this q-range (sums the 16 k-blocks' partials)
  if (threadIdx.x < QROWS) {
    const float* zp = zpart + (size_t)p * NKB * QROWS + threadIdx.x;
    float z = 0.f;
#pragma unroll
    for (int kb = 0; kb < NKB; ++kb) z += zp[(size_t)kb * QROWS];
    invZ[threadIdx.x] = 1.0f / z;
  }
  __syncthreads();

  int qloc0 = wave * 32;
  const __bf16* Qp = Qb + ((size_t)b * SLEN + qr * QROWS + qloc0) * DDIM;

  v8bf qf[2][4];
#pragma unroll
  for (int qs = 0; qs < 2; ++qs)
#pragma unroll
    for (int hs = 0; hs < 4; ++hs)
      qf[qs][hs] = *reinterpret_cast<const v8bf*>(Qp + (size_t)(qs * 16 + lr) * DDIM + hs * 32 + lg * 8);

  float iz[2][4];
#pragma unroll
  for (int qs = 0; qs < 2; ++qs)
#pragma unroll
    for (int j = 0; j < 4; ++j)
      iz[qs][j] = invZ[qloc0 + qs * 16 + lg * 4 + j];

  const char* pa[4];
#pragma unroll
  for (int hs = 0; hs < 4; ++hs)
    pa[hs] = kbuf + lr * 256 + (((hs * 4 + lg) ^ (lr & 7)) << 4);

  float* wbase = &warr[wave][lr];

  auto cw = [&](const f32x4 A[2], int t) {
    float wk = 0.f;
#pragma unroll
    for (int qs = 0; qs < 2; ++qs)
#pragma unroll
      for (int j = 0; j < 4; ++j)
        wk += exp2f(A[qs][j]) * iz[qs][j];
    wk += __shfl_xor(wk, 16);
    wk += __shfl_xor(wk, 32);
    if (lg == 0) wbase[t * 16] = wk;
  };

  v8bf kA[4], kB[4];
  f32x4 aA[2], aB[2];
  read4(kA, pa, 0);
  read4(kB, pa, 1);
  mfma8(aA, qf, kA);          // t0
#pragma unroll 1
  for (int i = 0; i < 7; ++i) {
    read4(kA, pa, 2 * i + 2);
    mfma8(aB, qf, kB);        // t(2i+1)
    cw(aA, 2 * i);            // t(2i)
    read4(kB, pa, 2 * i + 3);
    mfma8(aA, qf, kA);        // t(2i+2)
    cw(aB, 2 * i + 1);        // t(2i+1)
  }
  mfma8(aB, qf, kB);          // t15
  cw(aA, 14);
  cw(aB, 15);

  __syncthreads();
  if (threadIdx.x < KROWS) {
    int k = threadIdx.x;
    float s = 0.f;
#pragma unroll
    for (int w = 0; w < NW; ++w) s += warr[w][k];
    wpart[(size_t)p * SLEN + kblk * KROWS + k] = s;
  }
}

// ---------------------------------------------------------------------------
// k4: fused column-sum (16 q-range slabs) + weighted x reduction.
// 16x4 blocks x 256 threads: block (b, kc) covers 256 k-rows.
__global__ __launch_bounds__(256) void k4_u(const float* __restrict__ x,
                                            const float* __restrict__ wpart,
                                            float* __restrict__ upart) {
  int b = blockIdx.y, kc = blockIdx.x;   // kc: 16 chunks of 256 k
  int t = threadIdx.x;
  __shared__ float ws[256];
  {
    const float* pw = wpart + (size_t)b * NQR * SLEN + kc * 256 + t;
    float s = 0.f;
#pragma unroll
    for (int j = 0; j < NQR; ++j) s += pw[(size_t)j * SLEN];
    ws[t] = s;
  }
  __syncthreads();
  int d = t & 127, kh = t >> 7;   // 2 k-halves of 128
  const float* xb = x + ((size_t)b * SLEN + kc * 256 + kh * 128) * DDIM;
  float acc = 0.f;
  for (int kk = 0; kk < 128; ++kk)
    acc += ws[kh * 128 + kk] * xb[(size_t)kk * DDIM + d];
  upart[((size_t)b * 32 + kc * 2 + kh) * DDIM + d] = acc;
}

// ---------------------------------------------------------------------------
// k5: out[b,d] = (1/S) * (u[b,:] @ Wv[:,d]) + bv[d]
__global__ __launch_bounds__(128) void k5_out(const float* __restrict__ upart,
                                              const float* __restrict__ Wv,
                                              const float* __restrict__ bv,
                                              float* __restrict__ out) {
  int b = blockIdx.x, d = threadIdx.x;
  __shared__ float u[DDIM];
  float s = 0.f;
  for (int c = 0; c < 32; ++c) s += upart[((size_t)b * 32 + c) * DDIM + d];
  u[d] = s;
  __syncthreads();
  float acc = 0.f;
  for (int dp = 0; dp < DDIM; ++dp) acc += u[dp] * Wv[(size_t)dp * DDIM + d];
  out[b * DDIM + d] = acc * (1.0f / SLEN) + bv[d];
}

// ---------------------------------------------------------------------------
extern "C" void kernel_launch(void* const* d_in, const int* in_sizes, int n_in,
                              void* d_out, int out_size, void* d_ws, size_t ws_size,
                              hipStream_t stream) {
  const float* x  = (const float*)d_in[0];
  const float* Wq = (const float*)d_in[1];
  const float* bq = (const float*)d_in[2];
  const float* Wk = (const float*)d_in[3];
  const float* bk = (const float*)d_in[4];
  const float* Wv = (const float*)d_in[5];
  const float* bv = (const float*)d_in[6];
  float* out = (float*)d_out;

  char* ws = (char*)d_ws;
  __bf16* Qb    = (__bf16*)(ws);                                  // 4 MB
  __bf16* Kb    = (__bf16*)(ws + (4u << 20));                     // 4 MB
  float*  zpart = (float*)(ws + (8u << 20));                      // 1 MB
  float*  wpart = (float*)(ws + (9u << 20));                      // 1 MB
  float*  upart = (float*)(ws + (10u << 20));                     // 64 KB

  k1_proj<<<256, 256, 0, stream>>>(x, Wq, Wk, bq, bk, Qb, Kb);
  k2a_z  <<<NKB * NQR * BATCH, 512, 0, stream>>>(Qb, Kb, zpart);
  k2c_w  <<<NKB * NQR * BATCH, 512, 0, stream>>>(Qb, Kb, zpart, wpart);
  k4_u   <<<dim3(16, BATCH), 256, 0, stream>>>(x, wpart, upart);
  k5_out <<<BATCH, 128, 0, stream>>>(upart, Wv, bv, out);
}